// Round 6
// baseline (124.657 us; speedup 1.0000x reference)
//
#include <hip/hip_runtime.h>
#include <hip/hip_cooperative_groups.h>
#include <hip/hip_bf16.h>
#include <math.h>

namespace cg = cooperative_groups;

#define B_ 128
#define IN_ 1024
#define D_ 128
#define H_ 512
#define S_ 256

typedef __attribute__((ext_vector_type(8))) short short8v;
typedef __attribute__((ext_vector_type(8))) unsigned short ushort8v;
typedef __attribute__((ext_vector_type(4))) unsigned short ushort4v;
typedef __attribute__((ext_vector_type(4))) float f32x4;

__device__ __forceinline__ float softplusf(float x) {
  return fmaxf(x, 0.f) + log1pf(expf(-fabsf(x)));
}

__device__ __forceinline__ unsigned short f2bf(float f) {
  unsigned u = __float_as_uint(f);
  unsigned r = (u + 0x7fff + ((u >> 16) & 1)) >> 16;   // RNE
  return (unsigned short)r;
}

union SMem {
  struct { float xs[IN_]; float p2[512]; float red[8]; } pw;
  struct { float wsA[128]; float wsB[128]; float red2[8][2]; } px;
  struct { float zs[512]; float ws2[512]; float fz[8][4]; } zw;
  struct {
    unsigned short atile[128 * 128];   // 32 KB, XOR-swizzled bf16
    float zb1s[H_]; float w2s[H_];
    float red[8][64]; float mred[2]; float ered[2];
  } mn;
};

// One cooperative kernel: 256 blocks x 512 threads.
// Phase A: prep (Bp pack / pwx / pxw / zw) split by block range.
// Phase B: MFMA GEMM, block = (b, s-half of 128), -> (max, sumexp) partials.
// Phase C: block 0 combines -> out[b].
__global__ __launch_bounds__(512) void Kall(
    const float* __restrict__ x, const float* __restrict__ w,
    const float* __restrict__ z, const float* __restrict__ wt,
    const float* __restrict__ W, const float* __restrict__ bvec,
    const float* __restrict__ cvec, const float* __restrict__ W1,
    const float* __restrict__ b1p, const float* __restrict__ W2,
    const float* __restrict__ b2p,
    unsigned short* __restrict__ Bp, float* __restrict__ zb1,
    float* __restrict__ mpart, float* __restrict__ lpart,
    float* __restrict__ pwx_s, float* __restrict__ pxw_s,
    float* __restrict__ fzw_s, float* __restrict__ out) {
  cg::grid_group grid = cg::this_grid();
  __shared__ SMem sm;
  const int blk = blockIdx.x;
  const int t = threadIdx.x;
  const int lane = t & 63, wv = t >> 6;

  // ================= phase A =================
  if (blk < 32) {
    // ---- pack Bp (verified layout): frag=hblk*4+ks, h=hblk*16+(l&15),
    // k=ks*32+(l>>4)*8+j
    const int o = (blk * 512 + t) * 4;
    const int frag = o >> 9;
    const int l = (o >> 3) & 63;
    const int j0 = o & 7;
    const int h = (frag >> 2) * 16 + (l & 15);
    const int k0 = (frag & 3) * 32 + ((l >> 4) << 3) + j0;
    const float4 v = *(const float4*)(W1 + (size_t)h * 256 + 128 + k0);
    ushort4v u;
    u[0] = f2bf(v.x); u[1] = f2bf(v.y); u[2] = f2bf(v.z); u[3] = f2bf(v.w);
    *(ushort4v*)(Bp + o) = u;
  } else if (blk < 160) {
    // ---- pwx, one b per block, fused to scalar
    const int b = blk - 32;
    sm.pw.xs[t] = x[b * IN_ + t];
    sm.pw.xs[512 + t] = x[b * IN_ + 512 + t];
    __syncthreads();
    const int d = t & 127, ks = t >> 7;          // ks 0..3, 256 i-rows each
    const float* __restrict__ Wp = W + (size_t)(ks * 256) * D_ + d;
    float s = 0.f;
    #pragma unroll 8
    for (int i = 0; i < 256; ++i) s = fmaf(sm.pw.xs[ks * 256 + i], Wp[(size_t)i * D_], s);
    sm.pw.p2[ks * 128 + d] = s;
    __syncthreads();
    if (t < 128) {
      const float lg = bvec[t] + sm.pw.p2[t] + sm.pw.p2[128 + t]
                     + sm.pw.p2[256 + t] + sm.pw.p2[384 + t];
      float term = w[b * 128 + t] * lg - softplusf(lg);
      #pragma unroll
      for (int o2 = 1; o2 < 64; o2 <<= 1) term += __shfl_xor(term, o2);
      if (lane == 0) sm.pw.red[wv] = term;
    }
    __syncthreads();
    if (t == 0) pwx_s[b] = sm.pw.red[0] + sm.pw.red[1];
  } else if (blk < 224) {
    // ---- pxw, 2 b per block sharing W-row loads, 16 lanes/row
    const int b0 = (blk - 160) * 2, bB = b0 + 1;
    if (t < 128) sm.px.wsA[t] = w[b0 * 128 + t];
    else if (t < 256) sm.px.wsB[t - 128] = w[bB * 128 + (t - 128)];
    __syncthreads();
    const int chunk = t & 15, rgrp = t >> 4;     // 32 rows in flight
    float wr0[8], wr1[8];
    #pragma unroll
    for (int j = 0; j < 8; ++j) {
      wr0[j] = sm.px.wsA[chunk * 8 + j];
      wr1[j] = sm.px.wsB[chunk * 8 + j];
    }
    float t0 = 0.f, t1 = 0.f;
    #pragma unroll 2
    for (int it = 0; it < 32; ++it) {
      const int i = it * 32 + rgrp;
      const float4* __restrict__ rp = (const float4*)(W + (size_t)i * D_ + chunk * 8);
      const float4 va = rp[0], vb = rp[1];
      float d0 = 0.f, d1 = 0.f;
      d0 = fmaf(va.x, wr0[0], d0); d0 = fmaf(va.y, wr0[1], d0);
      d0 = fmaf(va.z, wr0[2], d0); d0 = fmaf(va.w, wr0[3], d0);
      d0 = fmaf(vb.x, wr0[4], d0); d0 = fmaf(vb.y, wr0[5], d0);
      d0 = fmaf(vb.z, wr0[6], d0); d0 = fmaf(vb.w, wr0[7], d0);
      d1 = fmaf(va.x, wr1[0], d1); d1 = fmaf(va.y, wr1[1], d1);
      d1 = fmaf(va.z, wr1[2], d1); d1 = fmaf(va.w, wr1[3], d1);
      d1 = fmaf(vb.x, wr1[4], d1); d1 = fmaf(vb.y, wr1[5], d1);
      d1 = fmaf(vb.z, wr1[6], d1); d1 = fmaf(vb.w, wr1[7], d1);
      d0 += __shfl_xor(d0, 1); d0 += __shfl_xor(d0, 2);
      d0 += __shfl_xor(d0, 4); d0 += __shfl_xor(d0, 8);
      d1 += __shfl_xor(d1, 1); d1 += __shfl_xor(d1, 2);
      d1 += __shfl_xor(d1, 4); d1 += __shfl_xor(d1, 8);
      if (chunk == 0) {
        const float lg0 = d0 + cvec[i];
        t0 += x[b0 * IN_ + i] * lg0 - softplusf(lg0);
        const float lg1 = d1 + cvec[i];
        t1 += x[bB * IN_ + i] * lg1 - softplusf(lg1);
      }
    }
    #pragma unroll
    for (int o2 = 1; o2 < 64; o2 <<= 1) {
      t0 += __shfl_xor(t0, o2);
      t1 += __shfl_xor(t1, o2);
    }
    if (lane == 0) { sm.px.red2[wv][0] = t0; sm.px.red2[wv][1] = t1; }
    __syncthreads();
    if (t == 0) {
      float s0 = 0.f, s1 = 0.f;
      #pragma unroll
      for (int w8 = 0; w8 < 8; ++w8) { s0 += sm.px.red2[w8][0]; s1 += sm.px.red2[w8][1]; }
      pxw_s[b0] = s0; pxw_s[bB] = s1;
    }
  } else {
    // ---- zw: 4 b per block sharing W1-row loads; zb1 + complete fzw
    const int b0 = (blk - 224) * 4;
    sm.zw.zs[t] = z[b0 * 128 + t];
    sm.zw.ws2[t] = w[b0 * 128 + t];
    __syncthreads();
    const int c16 = t & 15, rgrp = t >> 4;       // 32 rows in flight
    float reg[4][16];
    #pragma unroll
    for (int bb = 0; bb < 4; ++bb)
      #pragma unroll
      for (int j = 0; j < 16; ++j)
        reg[bb][j] = (c16 < 8) ? sm.zw.zs[bb * 128 + c16 * 16 + j]
                               : sm.zw.ws2[bb * 128 + (c16 - 8) * 16 + j];
    float fpacc[4] = {0.f, 0.f, 0.f, 0.f};
    for (int it = 0; it < 16; ++it) {
      const int h = it * 32 + rgrp;
      const float4* __restrict__ rp = (const float4*)(W1 + (size_t)h * 256 + c16 * 16);
      const float4 v0 = rp[0], v1 = rp[1], v2 = rp[2], v3 = rp[3];
      float dt[4];
      #pragma unroll
      for (int bb = 0; bb < 4; ++bb) {
        float dd = 0.f;
        dd = fmaf(v0.x, reg[bb][0], dd);  dd = fmaf(v0.y, reg[bb][1], dd);
        dd = fmaf(v0.z, reg[bb][2], dd);  dd = fmaf(v0.w, reg[bb][3], dd);
        dd = fmaf(v1.x, reg[bb][4], dd);  dd = fmaf(v1.y, reg[bb][5], dd);
        dd = fmaf(v1.z, reg[bb][6], dd);  dd = fmaf(v1.w, reg[bb][7], dd);
        dd = fmaf(v2.x, reg[bb][8], dd);  dd = fmaf(v2.y, reg[bb][9], dd);
        dd = fmaf(v2.z, reg[bb][10], dd); dd = fmaf(v2.w, reg[bb][11], dd);
        dd = fmaf(v3.x, reg[bb][12], dd); dd = fmaf(v3.y, reg[bb][13], dd);
        dd = fmaf(v3.z, reg[bb][14], dd); dd = fmaf(v3.w, reg[bb][15], dd);
        dd += __shfl_xor(dd, 1); dd += __shfl_xor(dd, 2); dd += __shfl_xor(dd, 4);
        dt[bb] = dd;
      }
      #pragma unroll
      for (int bb = 0; bb < 4; ++bb) {
        const float oth = __shfl_xor(dt[bb], 8);   // pair z-dot with w-dot
        if (c16 == 0) {
          const float zp = dt[bb] + b1p[h];
          zb1[(size_t)(b0 + bb) * H_ + h] = zp;
          fpacc[bb] += fmaxf(zp + oth, 0.f) * W2[h];
        }
      }
    }
    #pragma unroll
    for (int bb = 0; bb < 4; ++bb) {
      fpacc[bb] += __shfl_xor(fpacc[bb], 16);
      fpacc[bb] += __shfl_xor(fpacc[bb], 32);
    }
    if (lane == 0) {
      #pragma unroll
      for (int bb = 0; bb < 4; ++bb) sm.zw.fz[wv][bb] = fpacc[bb];
    }
    __syncthreads();
    if (t < 4) {
      float s = 0.f;
      #pragma unroll
      for (int w8 = 0; w8 < 8; ++w8) s += sm.zw.fz[w8][t];
      fzw_s[b0 + t] = s + b2p[0];
    }
  }
  grid.sync();

  // ================= phase B: GEMM, block = (b, s-half) =================
  {
    const int b = blk & 127, sh = blk >> 7;
    const int sc = wv >> 2, nh = (wv >> 1) & 1, nth = wv & 1;

    sm.mn.zb1s[t] = zb1[(size_t)b * H_ + t];
    sm.mn.w2s[t] = W2[t];

    // stage A: 128 rows x 128 d, fp32 -> bf16, granule swizzle g ^= r&15
    {
      const int r = t >> 2;                      // 0..127
      const int g0 = (t & 3) * 4;
      const float* __restrict__ src = wt + ((size_t)(sh * 128 + r) * B_ + b) * D_;
      #pragma unroll
      for (int gg = 0; gg < 4; ++gg) {
        const int g = g0 + gg;
        const float4 v0 = *(const float4*)(src + g * 8);
        const float4 v1 = *(const float4*)(src + g * 8 + 4);
        ushort8v u;
        u[0] = f2bf(v0.x); u[1] = f2bf(v0.y); u[2] = f2bf(v0.z); u[3] = f2bf(v0.w);
        u[4] = f2bf(v1.x); u[5] = f2bf(v1.y); u[6] = f2bf(v1.z); u[7] = f2bf(v1.w);
        *(ushort8v*)&sm.mn.atile[r * 128 + ((g ^ (r & 15)) << 3)] = u;
      }
    }
    __syncthreads();

    short8v afr[4][4];
    #pragma unroll
    for (int m = 0; m < 4; ++m) {
      const int arow = sc * 64 + m * 16 + (lane & 15);
      #pragma unroll
      for (int ks = 0; ks < 4; ++ks) {
        const int g = ks * 4 + (lane >> 4);
        afr[m][ks] = *(const short8v*)&sm.mn.atile[arow * 128 + ((g ^ (arow & 15)) << 3)];
      }
    }

    float fsum[4][4];
    #pragma unroll
    for (int m = 0; m < 4; ++m)
      #pragma unroll
      for (int j = 0; j < 4; ++j) fsum[m][j] = 0.f;

    const int hl = lane & 15;
    #pragma unroll 2
    for (int nt = 0; nt < 8; ++nt) {
      const int hblk = nh * 16 + nth * 8 + nt;
      const int hrow = hblk * 16 + hl;
      f32x4 acc0 = {0.f,0.f,0.f,0.f}, acc1 = {0.f,0.f,0.f,0.f};
      f32x4 acc2 = {0.f,0.f,0.f,0.f}, acc3 = {0.f,0.f,0.f,0.f};
      #pragma unroll
      for (int ks = 0; ks < 4; ++ks) {
        const int frag = hblk * 4 + ks;
        const short8v bfr = *(const short8v*)(Bp + ((size_t)frag << 9) + (lane << 3));
        acc0 = __builtin_amdgcn_mfma_f32_16x16x32_bf16(afr[0][ks], bfr, acc0, 0, 0, 0);
        acc1 = __builtin_amdgcn_mfma_f32_16x16x32_bf16(afr[1][ks], bfr, acc1, 0, 0, 0);
        acc2 = __builtin_amdgcn_mfma_f32_16x16x32_bf16(afr[2][ks], bfr, acc2, 0, 0, 0);
        acc3 = __builtin_amdgcn_mfma_f32_16x16x32_bf16(afr[3][ks], bfr, acc3, 0, 0, 0);
      }
      const float zv = sm.mn.zb1s[hrow], wgt = sm.mn.w2s[hrow];
      #pragma unroll
      for (int j = 0; j < 4; ++j) {
        fsum[0][j] += fmaxf(acc0[j] + zv, 0.f) * wgt;
        fsum[1][j] += fmaxf(acc1[j] + zv, 0.f) * wgt;
        fsum[2][j] += fmaxf(acc2[j] + zv, 0.f) * wgt;
        fsum[3][j] += fmaxf(acc3[j] + zv, 0.f) * wgt;
      }
    }
    #pragma unroll
    for (int m = 0; m < 4; ++m)
      #pragma unroll
      for (int j = 0; j < 4; ++j) {
        float v = fsum[m][j];
        v += __shfl_xor(v, 1); v += __shfl_xor(v, 2);
        v += __shfl_xor(v, 4); v += __shfl_xor(v, 8);
        fsum[m][j] = v;
      }
    if (hl == 0) {
      const int rb = (lane >> 4) * 4;
      #pragma unroll
      for (int m = 0; m < 4; ++m)
        #pragma unroll
        for (int j = 0; j < 4; ++j)
          sm.mn.red[wv][m * 16 + rb + j] = fsum[m][j];
    }
    __syncthreads();

    // per-block partial logsumexp over 128 f values
    float fval = 0.f;
    if (t < 128) {
      const int sc2 = t >> 6, r = t & 63;
      fval = sm.mn.red[sc2 * 4 + 0][r] + sm.mn.red[sc2 * 4 + 1][r]
           + sm.mn.red[sc2 * 4 + 2][r] + sm.mn.red[sc2 * 4 + 3][r] + b2p[0];
      float mm = fval;
      #pragma unroll
      for (int o2 = 1; o2 < 64; o2 <<= 1) mm = fmaxf(mm, __shfl_xor(mm, o2));
      if (lane == 0) sm.mn.mred[sc2] = mm;
    }
    __syncthreads();
    if (t < 128) {
      const float mm = fmaxf(sm.mn.mred[0], sm.mn.mred[1]);
      float e = expf(fval - mm);
      #pragma unroll
      for (int o2 = 1; o2 < 64; o2 <<= 1) e += __shfl_xor(e, o2);
      if (lane == 0) sm.mn.ered[t >> 6] = e;
    }
    __syncthreads();
    if (t == 0) {
      mpart[blk] = fmaxf(sm.mn.mred[0], sm.mn.mred[1]);
      lpart[blk] = sm.mn.ered[0] + sm.mn.ered[1];
    }
  }
  grid.sync();

  // ================= phase C: combine =================
  if (blk == 0 && t < 128) {
    const int b = t;
    const float m0 = mpart[b], m1 = mpart[128 + b];
    const float l0 = lpart[b], l1 = lpart[128 + b];
    const float mm = fmaxf(m0, m1);
    const float l = l0 * expf(m0 - mm) + l1 * expf(m1 - mm);
    const float logZ = mm + logf(l) - logf((float)S_) + (float)D_ * logf(2.f);
    const float r_wz = fminf(fzw_s[b] - logZ, 0.f);
    out[b] = -(pxw_s[b] - pwx_s[b] + r_wz);
  }
}

extern "C" void kernel_launch(void* const* d_in, const int* in_sizes, int n_in,
                              void* d_out, int out_size, void* d_ws, size_t ws_size,
                              hipStream_t stream) {
  const float* x    = (const float*)d_in[0];
  // d_in[1] = y, unused
  const float* w    = (const float*)d_in[2];
  const float* z    = (const float*)d_in[3];
  const float* wt   = (const float*)d_in[4];
  const float* W    = (const float*)d_in[5];
  const float* bvec = (const float*)d_in[6];
  const float* cvec = (const float*)d_in[7];
  const float* W1   = (const float*)d_in[8];
  const float* b1p  = (const float*)d_in[9];
  const float* W2   = (const float*)d_in[10];
  const float* b2p  = (const float*)d_in[11];

  float* ws_f = (float*)d_ws;
  float* zb1            = ws_f;                              // 65536 f
  unsigned short* Bp    = (unsigned short*)(ws_f + 65536);   // 65536 us (32768 f)
  float* mpart          = ws_f + 98304;                      // 256 f
  float* lpart          = ws_f + 98560;                      // 256 f
  float* pwx_s          = ws_f + 98816;                      // 128 f
  float* pxw_s          = ws_f + 98944;                      // 128 f
  float* fzw_s          = ws_f + 99072;                      // 128 f
  float* outp = (float*)d_out;

  void* args[] = {
    (void*)&x, (void*)&w, (void*)&z, (void*)&wt, (void*)&W, (void*)&bvec,
    (void*)&cvec, (void*)&W1, (void*)&b1p, (void*)&W2, (void*)&b2p,
    (void*)&Bp, (void*)&zb1, (void*)&mpart, (void*)&lpart,
    (void*)&pwx_s, (void*)&pxw_s, (void*)&fzw_s, (void*)&outp
  };
  hipLaunchCooperativeKernel((void*)Kall, dim3(256), dim3(512), args, 0u, stream);
}

// Round 7
// 37.242 us; speedup vs baseline: 3.3472x; 3.3472x over previous
//
#include <hip/hip_runtime.h>
#include <hip/hip_bf16.h>
#include <math.h>

#define B_ 128
#define IN_ 1024
#define D_ 128
#define H_ 512
#define S_ 256

typedef __attribute__((ext_vector_type(8))) short short8v;
typedef __attribute__((ext_vector_type(8))) unsigned short ushort8v;
typedef __attribute__((ext_vector_type(4))) unsigned short ushort4v;
typedef __attribute__((ext_vector_type(4))) float f32x4;

__device__ __forceinline__ float softplusf(float x) {
  return fmaxf(x, 0.f) + log1pf(expf(-fabsf(x)));
}

__device__ __forceinline__ unsigned short f2bf(float f) {
  unsigned u = __float_as_uint(f);
  unsigned r = (u + 0x7fff + ((u >> 16) & 1)) >> 16;   // RNE
  return (unsigned short)r;
}

// ============ fused prep kernel (round-5 verified version) ============
// [0,64)      : pack W1 w-half -> bf16 MFMA-fragment order Bp
// [64,1088)   : log_pwx partial logits  (b x kc-of-8, 128 i-rows each)
// [1088,1600) : log_pxw partials        (b x ic-of-4) — 16-lane/row coalesced
// [1600,1856) : zb1 + f_zw partials     (b-quad x hc-of-8) — 16-lane/row coalesced
__global__ __launch_bounds__(256) void Kprep(
    const float* __restrict__ x, const float* __restrict__ w,
    const float* __restrict__ z, const float* __restrict__ W,
    const float* __restrict__ cvec, const float* __restrict__ W1,
    const float* __restrict__ b1, const float* __restrict__ W2,
    unsigned short* __restrict__ Bp, float* __restrict__ l2part,
    float* __restrict__ pxw_part, float* __restrict__ zb1,
    float* __restrict__ fzw_part) {
  __shared__ float smem[1024];
  const int blk = blockIdx.x;
  const int t = threadIdx.x;

  if (blk < 64) {
    // ---- pack Bp (verified): frag=hblk*4+ks, h=hblk*16+(l&15), k=ks*32+(l>>4)*8+j
    const int o = (blk * 256 + t) * 4;
    const int frag = o >> 9;
    const int l = (o >> 3) & 63;
    const int j0 = o & 7;
    const int h = (frag >> 2) * 16 + (l & 15);
    const int k0 = (frag & 3) * 32 + ((l >> 4) << 3) + j0;
    const float4 v = *(const float4*)(W1 + (size_t)h * 256 + 128 + k0);
    ushort4v u;
    u[0] = f2bf(v.x); u[1] = f2bf(v.y); u[2] = f2bf(v.z); u[3] = f2bf(v.w);
    *(ushort4v*)(Bp + o) = u;
  } else if (blk < 1088) {
    // ---- pwx partial: (b, kc of 8): 128 i-rows
    const int bb = blk - 64;
    const int b = bb >> 3, kc = bb & 7;
    float* xs = smem;            // 128
    float* p2 = smem + 128;      // 256
    if (t < 128) xs[t] = x[b * IN_ + kc * 128 + t];
    __syncthreads();
    const int d = t & 127, ks = t >> 7;
    const float* __restrict__ Wp = W + (size_t)(kc * 128 + ks * 64) * D_ + d;
    float s = 0.f;
    #pragma unroll 8
    for (int i = 0; i < 64; ++i) s = fmaf(xs[ks * 64 + i], Wp[(size_t)i * D_], s);
    p2[ks * 128 + d] = s;
    __syncthreads();
    if (t < 128) l2part[((size_t)b * 8 + kc) * 128 + t] = p2[t] + p2[128 + t];
  } else if (blk < 1600) {
    // ---- pxw partial: (b, ic of 4), 16 lanes per i-row
    const int bb = blk - 1088;
    const int b = bb >> 2, ic = bb & 3;
    float* ws_ = smem;           // 128
    float* red = smem + 128;     // 4
    if (t < 128) ws_[t] = w[b * 128 + t];
    __syncthreads();
    const int chunk = t & 15, rgrp = t >> 4;
    float wreg[8];
    #pragma unroll
    for (int j = 0; j < 8; ++j) wreg[j] = ws_[chunk * 8 + j];
    float term = 0.f;
    #pragma unroll 2
    for (int it = 0; it < 16; ++it) {
      const int i = ic * 256 + it * 16 + rgrp;
      const float4* __restrict__ rp = (const float4*)(W + (size_t)i * D_ + chunk * 8);
      const float4 va = rp[0], vb = rp[1];
      float dot = 0.f;
      dot = fmaf(va.x, wreg[0], dot); dot = fmaf(va.y, wreg[1], dot);
      dot = fmaf(va.z, wreg[2], dot); dot = fmaf(va.w, wreg[3], dot);
      dot = fmaf(vb.x, wreg[4], dot); dot = fmaf(vb.y, wreg[5], dot);
      dot = fmaf(vb.z, wreg[6], dot); dot = fmaf(vb.w, wreg[7], dot);
      dot += __shfl_xor(dot, 1); dot += __shfl_xor(dot, 2);
      dot += __shfl_xor(dot, 4); dot += __shfl_xor(dot, 8);
      if (chunk == 0) {
        const float lg = dot + cvec[i];
        term += x[b * IN_ + i] * lg - softplusf(lg);
      }
    }
    #pragma unroll
    for (int o = 32; o > 0; o >>= 1) term += __shfl_down(term, o);
    const int lane = t & 63, wid = t >> 6;
    if (lane == 0) red[wid] = term;
    __syncthreads();
    if (t == 0) pxw_part[b * 4 + ic] = red[0] + red[1] + red[2] + red[3];
  } else {
    // ---- zw: (b-quad, hc of 8), wave = b, 16 lanes per h-row
    const int bb = blk - 1600;
    const int bq = bb >> 3, hc = bb & 7;
    float* zs  = smem;           // 512
    float* ws2 = smem + 512;     // 512
    for (int e = t; e < 512; e += 256) {
      zs[e]  = z[bq * 512 + e];
      ws2[e] = w[bq * 512 + e];
    }
    __syncthreads();
    const int bs = t >> 6, lane = t & 63;
    const int c16 = lane & 15, rsub = lane >> 4;
    const int b = bq * 4 + bs;
    float zreg[16];
    #pragma unroll
    for (int j = 0; j < 16; ++j)
      zreg[j] = (c16 < 8) ? zs[bs * 128 + c16 * 16 + j]
                          : ws2[bs * 128 + c16 * 16 - 128 + j];
    float fpacc = 0.f;
    #pragma unroll 2
    for (int it = 0; it < 16; ++it) {
      const int h = hc * 64 + it * 4 + rsub;
      const float4* __restrict__ rp = (const float4*)(W1 + (size_t)h * 256 + c16 * 16);
      float dot = 0.f;
      #pragma unroll
      for (int q = 0; q < 4; ++q) {
        const float4 v = rp[q];
        dot = fmaf(v.x, zreg[4 * q + 0], dot);
        dot = fmaf(v.y, zreg[4 * q + 1], dot);
        dot = fmaf(v.z, zreg[4 * q + 2], dot);
        dot = fmaf(v.w, zreg[4 * q + 3], dot);
      }
      dot += __shfl_xor(dot, 1); dot += __shfl_xor(dot, 2);
      dot += __shfl_xor(dot, 4);
      const float other = __shfl_xor(dot, 8);
      if (c16 == 0) {
        const float zp = dot + b1[h];
        zb1[(size_t)b * H_ + h] = zp;
        fpacc += fmaxf(zp + other, 0.f) * W2[h];
      }
    }
    fpacc += __shfl_xor(fpacc, 16);
    fpacc += __shfl_xor(fpacc, 32);
    if (lane == 0) fzw_part[b * 8 + hc] = fpacc;
  }
}

// ============ MFMA GEMM: 512 blocks x 256 thr, block = (b, s-quarter) ============
// 4 waves; wave wv owns h-blocks [wv*8, wv*8+8). 4 m-tiles x 8 nt x 4 ks MFMA.
// Emits per-(b,sq) partial (max, sumexp) of f over its 64 s-rows.
__global__ __launch_bounds__(256) void Kmfma(
    const float* __restrict__ wt, const unsigned short* __restrict__ Bp,
    const float* __restrict__ zb1, const float* __restrict__ W2,
    const float* __restrict__ b2, float* __restrict__ mpart,
    float* __restrict__ lpart) {
  const int blk = blockIdx.x;            // 512 = sq*128 + b
  const int b = blk & (B_ - 1);
  const int sq = blk >> 7;               // 0..3
  const int s0 = sq * 64;
  const int t = threadIdx.x;
  const int lane = t & 63, wv = t >> 6;  // 4 waves

  __shared__ unsigned short atile[64 * 128];   // 16 KB, XOR-swizzled bf16
  __shared__ float zb1s[H_];
  __shared__ float w2s[H_];
  __shared__ float red[4][64];

  zb1s[t] = zb1[(size_t)b * H_ + t];
  zb1s[256 + t] = zb1[(size_t)b * H_ + 256 + t];
  w2s[t] = W2[t];
  w2s[256 + t] = W2[256 + t];

  // stage A: 64 rows x 128 d, fp32 -> bf16, granule swizzle g ^= r&15 (verified)
  {
    const int r = t >> 2;                // 0..63
    const int g0 = (t & 3) * 4;
    const float* __restrict__ src = wt + ((size_t)(s0 + r) * B_ + b) * D_;
    #pragma unroll
    for (int gg = 0; gg < 4; ++gg) {
      const int g = g0 + gg;
      const float4 v0 = *(const float4*)(src + g * 8);
      const float4 v1 = *(const float4*)(src + g * 8 + 4);
      ushort8v u;
      u[0] = f2bf(v0.x); u[1] = f2bf(v0.y); u[2] = f2bf(v0.z); u[3] = f2bf(v0.w);
      u[4] = f2bf(v1.x); u[5] = f2bf(v1.y); u[6] = f2bf(v1.z); u[7] = f2bf(v1.w);
      *(ushort8v*)&atile[r * 128 + ((g ^ (r & 15)) << 3)] = u;
    }
  }
  __syncthreads();

  // A fragments (verified mapping): row = m*16 + (lane&15), k = ks*32 + (lane>>4)*8 + j
  short8v afr[4][4];
  #pragma unroll
  for (int m = 0; m < 4; ++m) {
    const int arow = m * 16 + (lane & 15);
    #pragma unroll
    for (int ks = 0; ks < 4; ++ks) {
      const int g = ks * 4 + (lane >> 4);
      afr[m][ks] = *(const short8v*)&atile[arow * 128 + ((g ^ (arow & 15)) << 3)];
    }
  }

  float fsum[4][4];
  #pragma unroll
  for (int m = 0; m < 4; ++m)
    #pragma unroll
    for (int j = 0; j < 4; ++j) fsum[m][j] = 0.f;

  const int hl = lane & 15;
  #pragma unroll 2
  for (int nt = 0; nt < 8; ++nt) {
    const int hblk = wv * 8 + nt;        // 0..31
    const int hrow = hblk * 16 + hl;
    f32x4 acc0 = {0.f,0.f,0.f,0.f}, acc1 = {0.f,0.f,0.f,0.f};
    f32x4 acc2 = {0.f,0.f,0.f,0.f}, acc3 = {0.f,0.f,0.f,0.f};
    #pragma unroll
    for (int ks = 0; ks < 4; ++ks) {
      const int frag = hblk * 4 + ks;
      const short8v bfr = *(const short8v*)(Bp + ((size_t)frag << 9) + (lane << 3));
      acc0 = __builtin_amdgcn_mfma_f32_16x16x32_bf16(afr[0][ks], bfr, acc0, 0, 0, 0);
      acc1 = __builtin_amdgcn_mfma_f32_16x16x32_bf16(afr[1][ks], bfr, acc1, 0, 0, 0);
      acc2 = __builtin_amdgcn_mfma_f32_16x16x32_bf16(afr[2][ks], bfr, acc2, 0, 0, 0);
      acc3 = __builtin_amdgcn_mfma_f32_16x16x32_bf16(afr[3][ks], bfr, acc3, 0, 0, 0);
    }
    const float zv = zb1s[hrow], wgt = w2s[hrow];
    #pragma unroll
    for (int j = 0; j < 4; ++j) {
      fsum[0][j] += fmaxf(acc0[j] + zv, 0.f) * wgt;
      fsum[1][j] += fmaxf(acc1[j] + zv, 0.f) * wgt;
      fsum[2][j] += fmaxf(acc2[j] + zv, 0.f) * wgt;
      fsum[3][j] += fmaxf(acc3[j] + zv, 0.f) * wgt;
    }
  }
  // reduce over 16 h-columns (lane bits 0..3)
  #pragma unroll
  for (int m = 0; m < 4; ++m)
    #pragma unroll
    for (int j = 0; j < 4; ++j) {
      float v = fsum[m][j];
      v += __shfl_xor(v, 1); v += __shfl_xor(v, 2);
      v += __shfl_xor(v, 4); v += __shfl_xor(v, 8);
      fsum[m][j] = v;
    }
  if (hl == 0) {
    const int rb = (lane >> 4) * 4;
    #pragma unroll
    for (int m = 0; m < 4; ++m)
      #pragma unroll
      for (int j = 0; j < 4; ++j)
        red[wv][m * 16 + rb + j] = fsum[m][j];
  }
  __syncthreads();

  // partial logsumexp over this block's 64 f values (wave 0 only)
  if (t < 64) {
    const float fval = red[0][t] + red[1][t] + red[2][t] + red[3][t] + b2[0];
    float mm = fval;
    #pragma unroll
    for (int o = 1; o < 64; o <<= 1) mm = fmaxf(mm, __shfl_xor(mm, o));
    float e = expf(fval - mm);
    #pragma unroll
    for (int o = 1; o < 64; o <<= 1) e += __shfl_xor(e, o);
    if (t == 0) { mpart[blk] = mm; lpart[blk] = e; }
  }
}

// ============ finisher: 128 blocks x 128 thr ============
__global__ __launch_bounds__(128) void Kfin(
    const float* __restrict__ mpart, const float* __restrict__ lpart,
    const float* __restrict__ l2part, const float* __restrict__ bvec,
    const float* __restrict__ w, const float* __restrict__ pxw_part,
    const float* __restrict__ fzw_part, const float* __restrict__ b2,
    float* __restrict__ out) {
  const int b = blockIdx.x, t = threadIdx.x;
  __shared__ float red3[2];
  const int lane = t & 63, wid = t >> 6;
  // pwx finish
  float lg = bvec[t];
  #pragma unroll
  for (int kc = 0; kc < 8; ++kc) lg += l2part[((size_t)b * 8 + kc) * 128 + t];
  float term = w[b * 128 + t] * lg - softplusf(lg);
  #pragma unroll
  for (int o = 1; o < 64; o <<= 1) term += __shfl_xor(term, o);
  if (lane == 0) red3[wid] = term;
  __syncthreads();
  if (t == 0) {
    const float pwx = red3[0] + red3[1];
    // combine 4 logsumexp partials
    const float m0 = mpart[b], m1 = mpart[128 + b],
                m2 = mpart[256 + b], m3 = mpart[384 + b];
    const float mm = fmaxf(fmaxf(m0, m1), fmaxf(m2, m3));
    const float l = lpart[b] * expf(m0 - mm) + lpart[128 + b] * expf(m1 - mm)
                  + lpart[256 + b] * expf(m2 - mm) + lpart[384 + b] * expf(m3 - mm);
    const float logZ = mm + logf(l) - logf((float)S_) + (float)D_ * logf(2.f);
    const float pxw = pxw_part[b * 4] + pxw_part[b * 4 + 1]
                    + pxw_part[b * 4 + 2] + pxw_part[b * 4 + 3];
    const float fzw = fzw_part[b * 8 + 0] + fzw_part[b * 8 + 1] + fzw_part[b * 8 + 2]
                    + fzw_part[b * 8 + 3] + fzw_part[b * 8 + 4] + fzw_part[b * 8 + 5]
                    + fzw_part[b * 8 + 6] + fzw_part[b * 8 + 7] + b2[0];
    const float r_wz = fminf(fzw - logZ, 0.f);
    out[b] = -(pxw - pwx + r_wz);
  }
}

extern "C" void kernel_launch(void* const* d_in, const int* in_sizes, int n_in,
                              void* d_out, int out_size, void* d_ws, size_t ws_size,
                              hipStream_t stream) {
  const float* x    = (const float*)d_in[0];
  // d_in[1] = y, unused
  const float* w    = (const float*)d_in[2];
  const float* z    = (const float*)d_in[3];
  const float* wt   = (const float*)d_in[4];
  const float* W    = (const float*)d_in[5];
  const float* bvec = (const float*)d_in[6];
  const float* cvec = (const float*)d_in[7];
  const float* W1   = (const float*)d_in[8];
  const float* b1   = (const float*)d_in[9];
  const float* W2   = (const float*)d_in[10];
  const float* b2   = (const float*)d_in[11];

  float* ws_f = (float*)d_ws;
  float* zb1            = ws_f;                              // 65536 f
  unsigned short* Bp    = (unsigned short*)(ws_f + 65536);   // 65536 us (32768 f)
  float* l2part         = ws_f + 98304;                      // 131072 f
  float* pxw_part       = ws_f + 229376;                     // 512 f
  float* fzw_part       = ws_f + 229888;                     // 1024 f
  float* mpart          = ws_f + 230912;                     // 512 f
  float* lpart          = ws_f + 231424;                     // 512 f
  float* out = (float*)d_out;

  hipLaunchKernelGGL(Kprep, dim3(1856), dim3(256), 0, stream,
                     x, w, z, W, cvec, W1, b1, W2, Bp, l2part, pxw_part, zb1, fzw_part);
  hipLaunchKernelGGL(Kmfma, dim3(512), dim3(256), 0, stream,
                     wt, Bp, zb1, W2, b2, mpart, lpart);
  hipLaunchKernelGGL(Kfin, dim3(B_), dim3(128), 0, stream,
                     mpart, lpart, l2part, bvec, w, pxw_part, fzw_part, b2, out);
}